// Round 1
// baseline (5224.429 us; speedup 1.0000x reference)
//
#include <hip/hip_runtime.h>

// LSTM B=1024 T=512 H=256, input_size=1, output_size=1.
// Design (R1): sync-free batch-partitioned persistent blocks.
//  - 64 blocks x 256 threads (4 waves); each block owns 16 batch rows for all 512 steps.
//  - Per step: gates[16,1024] = h[16,256] @ W_hh^T via mfma_f32_16x16x32_bf16.
//  - W_hh pre-converted to bf16 fragment-order in d_ws (wconv_kernel); per wave
//    16 N-tiles x 8 K-frags = 128 KB; RES_TILES of them register-resident, rest
//    streamed from L2 each step (the per-CU L2 path is the predicted bound).
//  - Tile->wave assignment puts i/f/g/o of a hidden unit in the SAME lane+reg:
//    wave w owns N-tiles {16*gc + (w+4*g4)} so c/h updates are lane-local fp32.
//  - h round-trips through LDS (bf16, double-buffered, stride 264 to break bank
//    conflicts); ONE __syncthreads per timestep.

#define HID 256
#define TSTEPS 512
#define BROWS 16
#define NBLK 64
#define THREADS 256
#define RES_TILES 6      // register-resident N-tiles per wave (of 16)
#define HPAD 264         // hbuf row stride (bf16 elems); 264*2B=528B -> 16B aligned, bank-offset 4/row

typedef float v4f __attribute__((ext_vector_type(4)));
typedef unsigned int v4u __attribute__((ext_vector_type(4)));
typedef __bf16 v8bf __attribute__((ext_vector_type(8)));

__device__ __forceinline__ unsigned short f2bf(float f) {
    unsigned int u = __builtin_bit_cast(unsigned int, f);
    u += 0x7fffu + ((u >> 16) & 1u);   // RNE
    return (unsigned short)(u >> 16);
}
__device__ __forceinline__ float bf2f(unsigned short s) {
    unsigned int u = ((unsigned int)s) << 16;
    return __builtin_bit_cast(float, u);
}
__device__ __forceinline__ float fsigmoid(float x) {
    // 1/(1+exp(-x)); stable both tails (exp2->inf => rcp->0)
    float e = exp2f(x * -1.44269504f);
    return __builtin_amdgcn_rcpf(1.0f + e);
}
__device__ __forceinline__ float ftanh(float x) {
    // 1 - 2/(exp(2x)+1); stable both tails
    float e = exp2f(x * 2.88539008f);
    return 1.0f - 2.0f * __builtin_amdgcn_rcpf(1.0f + e);
}

// Convert W_hh fp32 [1024][256] -> bf16 in per-lane fragment order:
// Wbf[((Tn*8+kc)*64+lane)*8 + j] = bf16(W_hh[16*Tn+(lane&15)][32*kc+(lane>>4)*8+j])
// so the main kernel's B-fragment load is one coalesced dwordx4 per lane.
__global__ void wconv_kernel(const float* __restrict__ Whh,
                             unsigned short* __restrict__ Wbf) {
    int tid = blockIdx.x * blockDim.x + threadIdx.x;   // 0..32767
    int lane = tid & 63;
    int frag = tid >> 6;            // Tn*8+kc, 0..511
    int Tn = frag >> 3;
    int kc = frag & 7;
    int n  = Tn * 16 + (lane & 15);
    int kb = kc * 32 + (lane >> 4) * 8;
    const float* src = Whh + (size_t)n * HID + kb;
    unsigned short* dst = Wbf + (size_t)tid * 8;
#pragma unroll
    for (int j = 0; j < 8; ++j) dst[j] = f2bf(src[j]);
}

__global__ __launch_bounds__(THREADS, 1)
void lstm_kernel(const float* __restrict__ x,
                 const float* __restrict__ W_ih,
                 const float* __restrict__ b_ih,
                 const float* __restrict__ b_hh,
                 const float* __restrict__ W_lin,
                 const float* __restrict__ b_lin,
                 const unsigned short* __restrict__ Wbf,
                 float* __restrict__ out) {
    __shared__ __align__(16) unsigned short hbuf[2][BROWS * HPAD]; // bf16 h, double-buffered
    __shared__ __align__(16) float xT[TSTEPS * BROWS];             // x transposed: xT[t*16+m]
    __shared__ float part[THREADS];

    const int tid  = threadIdx.x;
    const int lane = tid & 63;
    const int w    = tid >> 6;      // wave 0..3
    const int l4   = lane & 15;
    const int quad = lane >> 4;
    const int r0   = blockIdx.x * BROWS;

    // Per-lane input-projection coefficients for each owned N-tile:
    // tile q = gc*4+g4  ->  Tn = 16*gc + (w + 4*g4),  n = 16*Tn + l4
    float wih_r[16], bias_r[16];
#pragma unroll
    for (int q = 0; q < 16; ++q) {
        int gc = q >> 2, g4 = q & 3;
        int Tn = 16 * gc + (w + 4 * g4);
        int n  = 16 * Tn + l4;
        wih_r[q]  = W_ih[n];
        bias_r[q] = b_ih[n] + b_hh[n];
    }

    // Register-resident W fragments (first RES_TILES tiles of this wave).
    v8bf wres[RES_TILES][8];
#pragma unroll
    for (int q = 0; q < RES_TILES; ++q) {
        int gc = q >> 2, g4 = q & 3;
        int Tn = 16 * gc + (w + 4 * g4);
#pragma unroll
        for (int kc = 0; kc < 8; ++kc) {
            const v4u* p = (const v4u*)(Wbf + ((size_t)(Tn * 8 + kc) * 64 + lane) * 8);
            wres[q][kc] = __builtin_bit_cast(v8bf, *p);
        }
    }

    // Stage this block's x slice into LDS, transposed (coalesced along t).
    for (int m = 0; m < BROWS; ++m) {
        for (int t = tid; t < TSTEPS; t += THREADS) {
            xT[t * BROWS + m] = x[(size_t)(r0 + m) * TSTEPS + t];
        }
    }
    // h(0) = 0
    for (int i = tid; i < BROWS * HPAD; i += THREADS) hbuf[0][i] = 0;
    __syncthreads();

    v4f acc[16];
    float c_st[4][4];   // [g4][r] : c[m=quad*4+r][j=16*(w+4*g4)+l4]
#pragma unroll
    for (int g4 = 0; g4 < 4; ++g4)
#pragma unroll
        for (int r = 0; r < 4; ++r) c_st[g4][r] = 0.0f;

    int cur = 0;
    for (int t = 0; t < TSTEPS; ++t) {
        // A fragments: A[m=l4][k=quad*8+j] from hbuf[cur]
        v8bf afrag[8];
        const unsigned short* hrow = &hbuf[cur][l4 * HPAD + quad * 8];
#pragma unroll
        for (int kc = 0; kc < 8; ++kc) {
            const v4u* p = (const v4u*)(hrow + kc * 32);
            afrag[kc] = __builtin_bit_cast(v8bf, *p);
        }
        // x for this step: lane needs rows m = quad*4 + 0..3
        v4f xr = *(const v4f*)(&xT[t * BROWS + quad * 4]);

        // acc init = x*W_ih + (b_ih+b_hh)
#pragma unroll
        for (int q = 0; q < 16; ++q) {
#pragma unroll
            for (int r = 0; r < 4; ++r)
                acc[q][r] = xr[r] * wih_r[q] + bias_r[q];
        }
        // gates += h @ W_hh^T
#pragma unroll
        for (int q = 0; q < 16; ++q) {
            if (q < RES_TILES) {
#pragma unroll
                for (int kc = 0; kc < 8; ++kc)
                    acc[q] = __builtin_amdgcn_mfma_f32_16x16x32_bf16(
                        afrag[kc], wres[q][kc], acc[q], 0, 0, 0);
            } else {
                int gc = q >> 2, g4 = q & 3;
                int Tn = 16 * gc + (w + 4 * g4);
#pragma unroll
                for (int kc = 0; kc < 8; ++kc) {
                    const v4u* p = (const v4u*)(Wbf + ((size_t)(Tn * 8 + kc) * 64 + lane) * 8);
                    v8bf bfr = __builtin_bit_cast(v8bf, *p);
                    acc[q] = __builtin_amdgcn_mfma_f32_16x16x32_bf16(
                        afrag[kc], bfr, acc[q], 0, 0, 0);
                }
            }
        }
        // Nonlinearities + state update; i/f/g/o for (g4,r) are lane-local.
        int nxt = cur ^ 1;
#pragma unroll
        for (int g4 = 0; g4 < 4; ++g4) {
            int j = 16 * (w + 4 * g4) + l4;
#pragma unroll
            for (int r = 0; r < 4; ++r) {
                float gi = fsigmoid(acc[0  + g4][r]);
                float gf = fsigmoid(acc[4  + g4][r]);
                float gg = ftanh   (acc[8  + g4][r]);
                float go = fsigmoid(acc[12 + g4][r]);
                float cn = gf * c_st[g4][r] + gi * gg;
                c_st[g4][r] = cn;
                float hn = go * ftanh(cn);
                int m = quad * 4 + r;
                hbuf[nxt][m * HPAD + j] = f2bf(hn);
            }
        }
        cur = nxt;
        __syncthreads();   // writers of h(t+1) done before readers at t+1
    }

    // Epilogue: out[b] = h_final . W_lin + b_lin   (h read back as bf16 from hbuf[cur])
    {
        int rrow = tid >> 4, s = tid & 15;
        float p = 0.0f;
#pragma unroll
        for (int jj = 0; jj < 16; ++jj) {
            int j = s * 16 + jj;
            p += bf2f(hbuf[cur][rrow * HPAD + j]) * W_lin[j];
        }
        part[tid] = p;
    }
    __syncthreads();
    if (tid < 16) {
        float sum = 0.0f;
#pragma unroll
        for (int s = 0; s < 16; ++s) sum += part[tid * 16 + s];
        out[r0 + tid] = sum + b_lin[0];
    }
}

extern "C" void kernel_launch(void* const* d_in, const int* in_sizes, int n_in,
                              void* d_out, int out_size, void* d_ws, size_t ws_size,
                              hipStream_t stream) {
    const float* x     = (const float*)d_in[0];
    const float* W_ih  = (const float*)d_in[1];
    const float* W_hh  = (const float*)d_in[2];
    const float* b_ih  = (const float*)d_in[3];
    const float* b_hh  = (const float*)d_in[4];
    const float* W_lin = (const float*)d_in[5];
    const float* b_lin = (const float*)d_in[6];
    unsigned short* Wbf = (unsigned short*)d_ws;   // 512 KB

    wconv_kernel<<<128, 256, 0, stream>>>(W_hh, Wbf);
    lstm_kernel<<<NBLK, THREADS, 0, stream>>>(x, W_ih, b_ih, b_hh, W_lin, b_lin,
                                              Wbf, (float*)d_out);
}

// Round 2
// 2774.300 us; speedup vs baseline: 1.8832x; 1.8832x over previous
//
#include <hip/hip_runtime.h>

// LSTM B=1024 T=512 H=256 (input_size=1, output_size=1) on MI355X.
// R2: 64 persistent blocks (1/CU) x 256 thr (4 waves); each block owns 16 batch
// rows for all 512 steps. Per step: gates[16,1024] = h[16,256] @ W_hh^T via
// mfma_f32_16x16x32_bf16. Per wave 16 N-tiles split:
//   q 0..6  register-resident (224 VGPR)
//   q 7..10 LDS-resident (staged once; 128 KB, ds_read_b128, no L2 traffic)
//   q 11..15 streamed from L2 each step via explicit 2-buffer rotation
// Gates processed in 4 per-g4 groups (i,f,g,o tiles of same hidden units) with
// eager nonlinearities -> only 4 v4f accumulators live at a time (R1's acc[16]
// + hoisted stream temps caused scratch spills: WRITE_SIZE 16.7 MB, 24k cy/step).
// h round-trips LDS (bf16, dbuf, stride 264); ONE __syncthreads per step.

#define HID 256
#define TT 512
#define BROWS 16
#define NBLK 64
#define THREADS 256
#define HPAD 264

typedef float v4f __attribute__((ext_vector_type(4)));
typedef unsigned int v4u __attribute__((ext_vector_type(4)));
typedef __bf16 v8bf __attribute__((ext_vector_type(8)));

__device__ __forceinline__ unsigned short f2bf(float f) {
    unsigned int u = __builtin_bit_cast(unsigned int, f);
    u += 0x7fffu + ((u >> 16) & 1u);   // RNE
    return (unsigned short)(u >> 16);
}
__device__ __forceinline__ float bf2f(unsigned short s) {
    unsigned int u = ((unsigned int)s) << 16;
    return __builtin_bit_cast(float, u);
}
__device__ __forceinline__ float fsigmoid(float x) {
    float e = exp2f(x * -1.44269504f);
    return __builtin_amdgcn_rcpf(1.0f + e);
}
__device__ __forceinline__ float ftanh(float x) {
    float e = exp2f(x * 2.88539008f);
    return 1.0f - 2.0f * __builtin_amdgcn_rcpf(1.0f + e);
}

// W_hh fp32 [1024][256] -> bf16 fragment order:
// Wbf[((Tn*8+kc)*64+lane)*8 + j] = bf16(W_hh[16*Tn+(lane&15)][32*kc+(lane>>4)*8+j])
__global__ void wconv_kernel(const float* __restrict__ Whh,
                             unsigned short* __restrict__ Wbf) {
    int tid = blockIdx.x * blockDim.x + threadIdx.x;   // 0..32767
    int lane = tid & 63;
    int frag = tid >> 6;
    int Tn = frag >> 3;
    int kc = frag & 7;
    int n  = Tn * 16 + (lane & 15);
    int kb = kc * 32 + (lane >> 4) * 8;
    const float* src = Whh + (size_t)n * HID + kb;
    unsigned short* dst = Wbf + (size_t)tid * 8;
#pragma unroll
    for (int j = 0; j < 8; ++j) dst[j] = f2bf(src[j]);
}

#define MFMA8(ACC, BARR, BOFF)                                               \
    _Pragma("unroll")                                                        \
    for (int kc = 0; kc < 8; ++kc)                                           \
        ACC = __builtin_amdgcn_mfma_f32_16x16x32_bf16(afrag[kc],             \
                  BARR[(BOFF) + kc], ACC, 0, 0, 0);

#define LDSTILE(ACC, SLOT)                                                   \
    { v8bf bl_[8];                                                           \
      _Pragma("unroll")                                                      \
      for (int kc = 0; kc < 8; ++kc)                                         \
          bl_[kc] = __builtin_bit_cast(v8bf, *(const v4u*)(Wlds +            \
                      ((size_t)(((w * 4 + (SLOT)) * 8 + kc) * 64 + lane)) * 8)); \
      MFMA8(ACC, bl_, 0) }

#define SLOAD(SB, Q)                                                         \
    _Pragma("unroll")                                                        \
    for (int kc = 0; kc < 8; ++kc)                                           \
        SB[kc] = __builtin_bit_cast(v8bf, *(const v4u*)(Wbf +                \
                   ((size_t)((16 * ((Q) >> 2) + w + 4 * ((Q) & 3)) * 8 + kc) \
                    * 64 + lane) * 8));

#define INITG(G4, AI, AF, AG, AO)                                            \
    { int nb = 16 * (w + 4 * (G4)) + l4;                                     \
      float w0 = gw[nb],       b0 = gb[nb];                                  \
      float w1 = gw[256 + nb], b1 = gb[256 + nb];                            \
      float w2 = gw[512 + nb], b2 = gb[512 + nb];                            \
      float w3 = gw[768 + nb], b3 = gb[768 + nb];                            \
      _Pragma("unroll")                                                      \
      for (int r = 0; r < 4; ++r) {                                          \
          AI[r] = xv[r] * w0 + b0; AF[r] = xv[r] * w1 + b1;                  \
          AG[r] = xv[r] * w2 + b2; AO[r] = xv[r] * w3 + b3; } }

#define GATES(G4, AI, AF, AG, AO)                                            \
    _Pragma("unroll")                                                        \
    for (int r = 0; r < 4; ++r) {                                            \
        float gi = fsigmoid(AI[r]);                                          \
        float gf = fsigmoid(AF[r]);                                          \
        float gg = ftanh(AG[r]);                                             \
        float go = fsigmoid(AO[r]);                                          \
        float cn = gf * c_st[(G4) * 4 + r] + gi * gg;                        \
        c_st[(G4) * 4 + r] = cn;                                             \
        hn_[(quad * 4 + r) * HPAD + 16 * (w + 4 * (G4)) + l4] =              \
            f2bf(go * ftanh(cn));                                            \
    }

__global__ __launch_bounds__(THREADS, 1)
void lstm_kernel(const float* __restrict__ x,
                 const float* __restrict__ W_ih,
                 const float* __restrict__ b_ih,
                 const float* __restrict__ b_hh,
                 const float* __restrict__ W_lin,
                 const float* __restrict__ b_lin,
                 const unsigned short* __restrict__ Wbf,
                 float* __restrict__ out) {
    __shared__ __align__(16) unsigned short Wlds[16 * 8 * 64 * 8];   // 128 KB
    __shared__ __align__(16) unsigned short hbuf[2][BROWS * HPAD];   // 16.9 KB
    __shared__ float gw[1024];                                       // 4 KB
    __shared__ float gb[1024];                                       // 4 KB
    __shared__ float part[THREADS];                                  // 1 KB

    const int tid  = threadIdx.x;
    const int lane = tid & 63;
    const int w    = tid >> 6;
    const int l4   = lane & 15;
    const int quad = lane >> 4;
    const int r0   = blockIdx.x * BROWS;

    // gate consts -> LDS
    for (int i = tid; i < 1024; i += THREADS) {
        gw[i] = W_ih[i];
        gb[i] = b_ih[i] + b_hh[i];
    }
    // h(0) = 0
    for (int i = tid; i < BROWS * HPAD; i += THREADS) hbuf[0][i] = 0;

    // register-resident tiles q=0..6
    v8bf wres[56];
#pragma unroll
    for (int q = 0; q < 7; ++q) {
        int Tn = 16 * (q >> 2) + w + 4 * (q & 3);
#pragma unroll
        for (int kc = 0; kc < 8; ++kc)
            wres[q * 8 + kc] = __builtin_bit_cast(v8bf, *(const v4u*)(Wbf +
                ((size_t)(Tn * 8 + kc) * 64 + lane) * 8));
    }
    // LDS-resident tiles: slots {0:q8, 1:q9, 2:q10, 3:q7}
    {
        const int slotq[4] = {8, 9, 10, 7};
#pragma unroll
        for (int s = 0; s < 4; ++s) {
            int q = slotq[s];
            int Tn = 16 * (q >> 2) + w + 4 * (q & 3);
#pragma unroll
            for (int kc = 0; kc < 8; ++kc) {
                v4u d = *(const v4u*)(Wbf + ((size_t)(Tn * 8 + kc) * 64 + lane) * 8);
                *(v4u*)(Wlds + ((size_t)(((w * 4 + s) * 8 + kc) * 64 + lane)) * 8) = d;
            }
        }
    }
    __syncthreads();

    float c_st[16];
#pragma unroll
    for (int i = 0; i < 16; ++i) c_st[i] = 0.0f;

    int cur = 0;
    for (int t = 0; t < TT; ++t) {
        const unsigned short* hb = hbuf[cur];
        unsigned short* hn_ = hbuf[cur ^ 1];

        // x for this step's 4 rows (L2-resident; same addr across l4 lanes)
        float xv[4];
#pragma unroll
        for (int r = 0; r < 4; ++r)
            xv[r] = x[(size_t)(r0 + quad * 4 + r) * TT + t];

        // stream prologue: issue tiles 12,13
        v8bf sb0[8], sb1[8];
        SLOAD(sb0, 12)
        SLOAD(sb1, 13)

        // A fragments from hbuf[cur]
        v8bf afrag[8];
        const unsigned short* hrow = hb + l4 * HPAD + quad * 8;
#pragma unroll
        for (int kc = 0; kc < 8; ++kc)
            afrag[kc] = __builtin_bit_cast(v8bf, *(const v4u*)(hrow + kc * 32));

        // ---- group 0 (tiles q0,q4,q8,q12) ----
        {
            v4f ai, af2, ag, ao;
            INITG(0, ai, af2, ag, ao)
            MFMA8(ai, wres, 0)      // q0
            MFMA8(af2, wres, 32)    // q4
            LDSTILE(ag, 0)          // q8
            MFMA8(ao, sb0, 0)       // T12
            SLOAD(sb0, 14)
            GATES(0, ai, af2, ag, ao)
        }
        // ---- group 1 (q1,q5,q9,q13) ----
        {
            v4f ai, af2, ag, ao;
            INITG(1, ai, af2, ag, ao)
            MFMA8(ai, wres, 8)      // q1
            MFMA8(af2, wres, 40)    // q5
            LDSTILE(ag, 1)          // q9
            MFMA8(ao, sb1, 0)       // T13
            SLOAD(sb1, 11)
            GATES(1, ai, af2, ag, ao)
        }
        // ---- group 2 (q2,q6,q10,q14) ----
        {
            v4f ai, af2, ag, ao;
            INITG(2, ai, af2, ag, ao)
            MFMA8(ai, wres, 16)     // q2
            MFMA8(af2, wres, 48)    // q6
            LDSTILE(ag, 2)          // q10
            MFMA8(ao, sb0, 0)       // T14
            SLOAD(sb0, 15)
            GATES(2, ai, af2, ag, ao)
        }
        // ---- group 3 (q3,q7,q11,q15) ----
        {
            v4f ai, af2, ag, ao;
            INITG(3, ai, af2, ag, ao)
            MFMA8(ai, wres, 24)     // q3
            LDSTILE(af2, 3)         // q7
            MFMA8(ag, sb1, 0)       // T11
            MFMA8(ao, sb0, 0)       // T15
            GATES(3, ai, af2, ag, ao)
        }

        cur ^= 1;
        __syncthreads();
    }

    // Epilogue: out[b] = h_final . W_lin + b_lin
    {
        int rrow = tid >> 4, s = tid & 15;
        float p = 0.0f;
#pragma unroll
        for (int jj = 0; jj < 16; ++jj) {
            int j = s * 16 + jj;
            p += bf2f(hbuf[cur][rrow * HPAD + j]) * W_lin[j];
        }
        part[tid] = p;
    }
    __syncthreads();
    if (tid < 16) {
        float sum = 0.0f;
#pragma unroll
        for (int s = 0; s < 16; ++s) sum += part[tid * 16 + s];
        out[r0 + tid] = sum + b_lin[0];
    }
}

extern "C" void kernel_launch(void* const* d_in, const int* in_sizes, int n_in,
                              void* d_out, int out_size, void* d_ws, size_t ws_size,
                              hipStream_t stream) {
    const float* x     = (const float*)d_in[0];
    const float* W_ih  = (const float*)d_in[1];
    const float* W_hh  = (const float*)d_in[2];
    const float* b_ih  = (const float*)d_in[3];
    const float* b_hh  = (const float*)d_in[4];
    const float* W_lin = (const float*)d_in[5];
    const float* b_lin = (const float*)d_in[6];
    unsigned short* Wbf = (unsigned short*)d_ws;   // 512 KB

    wconv_kernel<<<128, 256, 0, stream>>>(W_hh, Wbf);
    lstm_kernel<<<NBLK, THREADS, 0, stream>>>(x, W_ih, b_ih, b_hh, W_lin, b_lin,
                                              Wbf, (float*)d_out);
}

// Round 3
// 2607.540 us; speedup vs baseline: 2.0036x; 1.0640x over previous
//
#include <hip/hip_runtime.h>

// LSTM B=1024 T=512 H=256 (input_size=1, output_size=1) on MI355X.
// R3: 64 persistent blocks (1/CU) x 256 thr (4 waves, 1/SIMD); each block owns
// 16 batch rows for all 512 steps. gates[16,1024] = h[16,256] @ W_hh^T via
// mfma_f32_16x16x32_bf16. Per wave 16 N-tiles:
//   q0..q9   register-resident (320 regs; W frags are MFMA-B-only -> expect
//            RA to use AGPRs of the gfx950 unified 512-reg file at 1 wave/SIMD)
//   q10,q11,q14,q15  LDS-resident (128 KB, staged once)
//   q12,q13  streamed from L2 with CROSS-STEP prefetch: consumed in groups 0/1
//            (early), reloaded immediately after; loads stay in flight and are
//            drained by the barrier's vmcnt(0) instead of stalling mid-step.
// Eager per-g4 gate groups keep only 4 v4f accs live (R1 spilled: 16.7MB WRITE).
// h round-trips LDS (bf16, dbuf, stride 264); ONE __syncthreads per step.

#define HID 256
#define TT 512
#define BROWS 16
#define NBLK 64
#define THREADS 256
#define HPAD 264

typedef float v4f __attribute__((ext_vector_type(4)));
typedef unsigned int v4u __attribute__((ext_vector_type(4)));
typedef __bf16 v8bf __attribute__((ext_vector_type(8)));

__device__ __forceinline__ unsigned short f2bf(float f) {
    unsigned int u = __builtin_bit_cast(unsigned int, f);
    u += 0x7fffu + ((u >> 16) & 1u);   // RNE
    return (unsigned short)(u >> 16);
}
__device__ __forceinline__ float bf2f(unsigned short s) {
    unsigned int u = ((unsigned int)s) << 16;
    return __builtin_bit_cast(float, u);
}
__device__ __forceinline__ float fsigmoid(float x) {
    float e = exp2f(x * -1.44269504f);
    return __builtin_amdgcn_rcpf(1.0f + e);
}
__device__ __forceinline__ float ftanh(float x) {
    float e = exp2f(x * 2.88539008f);
    return 1.0f - 2.0f * __builtin_amdgcn_rcpf(1.0f + e);
}

// W_hh fp32 [1024][256] -> bf16 fragment order:
// Wbf[((Tn*8+kc)*64+lane)*8 + j] = bf16(W_hh[16*Tn+(lane&15)][32*kc+(lane>>4)*8+j])
__global__ void wconv_kernel(const float* __restrict__ Whh,
                             unsigned short* __restrict__ Wbf) {
    int tid = blockIdx.x * blockDim.x + threadIdx.x;   // 0..32767
    int lane = tid & 63;
    int frag = tid >> 6;
    int Tn = frag >> 3;
    int kc = frag & 7;
    int n  = Tn * 16 + (lane & 15);
    int kb = kc * 32 + (lane >> 4) * 8;
    const float* src = Whh + (size_t)n * HID + kb;
    unsigned short* dst = Wbf + (size_t)tid * 8;
#pragma unroll
    for (int j = 0; j < 8; ++j) dst[j] = f2bf(src[j]);
}

#define MFMA8(ACC, BARR, BOFF)                                               \
    _Pragma("unroll")                                                        \
    for (int kc = 0; kc < 8; ++kc)                                           \
        ACC = __builtin_amdgcn_mfma_f32_16x16x32_bf16(afrag[kc],             \
                  BARR[(BOFF) + kc], ACC, 0, 0, 0);

#define LDSTILE(ACC, SLOT)                                                   \
    { v8bf bl_[8];                                                           \
      _Pragma("unroll")                                                      \
      for (int kc = 0; kc < 8; ++kc)                                         \
          bl_[kc] = __builtin_bit_cast(v8bf, *(const v4u*)(Wlds +            \
                      ((size_t)(((w * 4 + (SLOT)) * 8 + kc) * 64 + lane)) * 8)); \
      MFMA8(ACC, bl_, 0) }

#define SLOAD(SB, Q)                                                         \
    _Pragma("unroll")                                                        \
    for (int kc = 0; kc < 8; ++kc)                                           \
        SB[kc] = __builtin_bit_cast(v8bf, *(const v4u*)(Wbf +                \
                   ((size_t)((16 * ((Q) >> 2) + w + 4 * ((Q) & 3)) * 8 + kc) \
                    * 64 + lane) * 8));

#define INITG(G4, AI, AF, AG, AO)                                            \
    { int nb = 16 * (w + 4 * (G4)) + l4;                                     \
      float w0 = gw[nb],       b0 = gb[nb];                                  \
      float w1 = gw[256 + nb], b1 = gb[256 + nb];                            \
      float w2 = gw[512 + nb], b2 = gb[512 + nb];                            \
      float w3 = gw[768 + nb], b3 = gb[768 + nb];                            \
      _Pragma("unroll")                                                      \
      for (int r = 0; r < 4; ++r) {                                          \
          AI[r] = xv[r] * w0 + b0; AF[r] = xv[r] * w1 + b1;                  \
          AG[r] = xv[r] * w2 + b2; AO[r] = xv[r] * w3 + b3; } }

#define GATES(G4, AI, AF, AG, AO)                                            \
    _Pragma("unroll")                                                        \
    for (int r = 0; r < 4; ++r) {                                            \
        float gi = fsigmoid(AI[r]);                                          \
        float gf = fsigmoid(AF[r]);                                          \
        float gg = ftanh(AG[r]);                                             \
        float go = fsigmoid(AO[r]);                                          \
        float cn = gf * c_st[(G4) * 4 + r] + gi * gg;                        \
        c_st[(G4) * 4 + r] = cn;                                             \
        hn_[(quad * 4 + r) * HPAD + 16 * (w + 4 * (G4)) + l4] =              \
            f2bf(go * ftanh(cn));                                            \
    }

__global__ __launch_bounds__(THREADS, 1)
void lstm_kernel(const float* __restrict__ x,
                 const float* __restrict__ W_ih,
                 const float* __restrict__ b_ih,
                 const float* __restrict__ b_hh,
                 const float* __restrict__ W_lin,
                 const float* __restrict__ b_lin,
                 const unsigned short* __restrict__ Wbf,
                 float* __restrict__ out) {
    __shared__ __align__(16) unsigned short Wlds[16 * 8 * 64 * 8];   // 128 KB
    __shared__ __align__(16) unsigned short hbuf[2][BROWS * HPAD];   // 16.9 KB
    __shared__ float gw[1024];                                       // 4 KB
    __shared__ float gb[1024];                                       // 4 KB
    __shared__ float part[THREADS];                                  // 1 KB

    const int tid  = threadIdx.x;
    const int lane = tid & 63;
    const int w    = tid >> 6;
    const int l4   = lane & 15;
    const int quad = lane >> 4;
    const int r0   = blockIdx.x * BROWS;

    // gate consts -> LDS
    for (int i = tid; i < 1024; i += THREADS) {
        gw[i] = W_ih[i];
        gb[i] = b_ih[i] + b_hh[i];
    }
    // h(0) = 0
    for (int i = tid; i < BROWS * HPAD; i += THREADS) hbuf[0][i] = 0;

    // register-resident tiles q=0..9 (320 regs; MFMA-B-only -> AGPR-eligible)
    v8bf wres[80];
#pragma unroll
    for (int q = 0; q < 10; ++q) {
        int Tn = 16 * (q >> 2) + w + 4 * (q & 3);
#pragma unroll
        for (int kc = 0; kc < 8; ++kc)
            wres[q * 8 + kc] = __builtin_bit_cast(v8bf, *(const v4u*)(Wbf +
                ((size_t)(Tn * 8 + kc) * 64 + lane) * 8));
    }
    // LDS-resident tiles: slots {0:q10, 1:q11, 2:q14, 3:q15}
    {
        const int slotq[4] = {10, 11, 14, 15};
#pragma unroll
        for (int s = 0; s < 4; ++s) {
            int q = slotq[s];
            int Tn = 16 * (q >> 2) + w + 4 * (q & 3);
#pragma unroll
            for (int kc = 0; kc < 8; ++kc) {
                v4u d = *(const v4u*)(Wbf + ((size_t)(Tn * 8 + kc) * 64 + lane) * 8);
                *(v4u*)(Wlds + ((size_t)(((w * 4 + s) * 8 + kc) * 64 + lane)) * 8) = d;
            }
        }
    }
    __syncthreads();

    float c_st[16];
#pragma unroll
    for (int i = 0; i < 16; ++i) c_st[i] = 0.0f;

    // streamed tiles q12,q13: prologue load; thereafter reloaded right after
    // each step's consumption so the loads ride across the barrier drain.
    v8bf sb0[8], sb1[8];
    SLOAD(sb0, 12)
    SLOAD(sb1, 13)

    int cur = 0;
    for (int t = 0; t < TT; ++t) {
        const unsigned short* hb = hbuf[cur];
        unsigned short* hn_ = hbuf[cur ^ 1];

        // x for this step's 4 rows (L1/L2-resident; uniform across l4 lanes)
        float xv[4];
#pragma unroll
        for (int r = 0; r < 4; ++r)
            xv[r] = x[(size_t)(r0 + quad * 4 + r) * TT + t];

        // A fragments from hbuf[cur]
        v8bf afrag[8];
        const unsigned short* hrow = hb + l4 * HPAD + quad * 8;
#pragma unroll
        for (int kc = 0; kc < 8; ++kc)
            afrag[kc] = __builtin_bit_cast(v8bf, *(const v4u*)(hrow + kc * 32));

        // ---- group 0 (i=q0, f=q4, g=q8, o=q12 streamed) ----
        {
            v4f ai, af2, ag, ao;
            INITG(0, ai, af2, ag, ao)
            MFMA8(ai, wres, 0)       // q0
            MFMA8(af2, wres, 32)     // q4
            MFMA8(ag, wres, 64)      // q8
            MFMA8(ao, sb0, 0)        // q12 (prefetched last step)
            SLOAD(sb0, 12)           // prefetch for t+1; in flight to barrier
            GATES(0, ai, af2, ag, ao)
        }
        // ---- group 1 (i=q1, f=q5, g=q9, o=q13 streamed) ----
        {
            v4f ai, af2, ag, ao;
            INITG(1, ai, af2, ag, ao)
            MFMA8(ai, wres, 8)       // q1
            MFMA8(af2, wres, 40)     // q5
            MFMA8(ag, wres, 72)      // q9
            MFMA8(ao, sb1, 0)        // q13
            SLOAD(sb1, 13)           // prefetch for t+1
            GATES(1, ai, af2, ag, ao)
        }
        // ---- group 2 (i=q2, f=q6, g=q10 LDS, o=q14 LDS) ----
        {
            v4f ai, af2, ag, ao;
            INITG(2, ai, af2, ag, ao)
            MFMA8(ai, wres, 16)      // q2
            MFMA8(af2, wres, 48)     // q6
            LDSTILE(ag, 0)           // q10
            LDSTILE(ao, 2)           // q14
            GATES(2, ai, af2, ag, ao)
        }
        // ---- group 3 (i=q3, f=q7, g=q11 LDS, o=q15 LDS) ----
        {
            v4f ai, af2, ag, ao;
            INITG(3, ai, af2, ag, ao)
            MFMA8(ai, wres, 24)      // q3
            MFMA8(af2, wres, 56)     // q7
            LDSTILE(ag, 1)           // q11
            LDSTILE(ao, 3)           // q15
            GATES(3, ai, af2, ag, ao)
        }

        cur ^= 1;
        __syncthreads();
    }

    // Epilogue: out[b] = h_final . W_lin + b_lin
    {
        int rrow = tid >> 4, s = tid & 15;
        float p = 0.0f;
#pragma unroll
        for (int jj = 0; jj < 16; ++jj) {
            int j = s * 16 + jj;
            p += bf2f(hbuf[cur][rrow * HPAD + j]) * W_lin[j];
        }
        part[tid] = p;
    }
    __syncthreads();
    if (tid < 16) {
        float sum = 0.0f;
#pragma unroll
        for (int s = 0; s < 16; ++s) sum += part[tid * 16 + s];
        out[r0 + tid] = sum + b_lin[0];
    }
}

extern "C" void kernel_launch(void* const* d_in, const int* in_sizes, int n_in,
                              void* d_out, int out_size, void* d_ws, size_t ws_size,
                              hipStream_t stream) {
    const float* x     = (const float*)d_in[0];
    const float* W_ih  = (const float*)d_in[1];
    const float* W_hh  = (const float*)d_in[2];
    const float* b_ih  = (const float*)d_in[3];
    const float* b_hh  = (const float*)d_in[4];
    const float* W_lin = (const float*)d_in[5];
    const float* b_lin = (const float*)d_in[6];
    unsigned short* Wbf = (unsigned short*)d_ws;   // 512 KB

    wconv_kernel<<<128, 256, 0, stream>>>(W_hh, Wbf);
    lstm_kernel<<<NBLK, THREADS, 0, stream>>>(x, W_ih, b_ih, b_hh, W_lin, b_lin,
                                              Wbf, (float*)d_out);
}

// Round 4
// 1583.908 us; speedup vs baseline: 3.2984x; 1.6463x over previous
//
#include <hip/hip_runtime.h>

// LSTM B=1024 T=512 H=256 (input_size=1, output_size=1) on MI355X.
// R4: TLP attack. R3 post-mortem: per-step 12.1k cy vs ~2k cy of issue work;
// 1 wave/SIMD exposes every latency. Now 64 blocks (1/CU) x 512 thr = 8 waves
// = 2 waves/SIMD; per-wave N-tiles 16 -> 8, sibling wave hides stalls.
// Per wave (w=0..7), tiles Tn(gc,S) = 16*gc + w + 8*S, gc=gate class, S=0,1:
//   i,f (gc0,gc1): register-resident, 4 tiles = 128 regs (MFMA-B-only)
//   g   (gc2):     LDS-resident, 16 tiles total = 128 KB staged once
//   o   (gc3):     streamed from L2 via ONE rotating 32-reg buffer:
//                  o0 cross-step prefetched, o1 loaded after o0 consumed.
// Hard 256-reg cap via __launch_bounds__(512,2) to hold 2 waves/SIMD.
// Eager per-(S) gate groups; lane-local c/h update; h via LDS bf16 dbuf
// (stride 264); ONE __syncthreads per step.

#define HID 256
#define TT 512
#define BROWS 16
#define NBLK 64
#define THREADS 512
#define HPAD 264

typedef float v4f __attribute__((ext_vector_type(4)));
typedef unsigned int v4u __attribute__((ext_vector_type(4)));
typedef __bf16 v8bf __attribute__((ext_vector_type(8)));

__device__ __forceinline__ unsigned short f2bf(float f) {
    unsigned int u = __builtin_bit_cast(unsigned int, f);
    u += 0x7fffu + ((u >> 16) & 1u);   // RNE
    return (unsigned short)(u >> 16);
}
__device__ __forceinline__ float bf2f(unsigned short s) {
    unsigned int u = ((unsigned int)s) << 16;
    return __builtin_bit_cast(float, u);
}
__device__ __forceinline__ float fsigmoid(float x) {
    float e = exp2f(x * -1.44269504f);
    return __builtin_amdgcn_rcpf(1.0f + e);
}
__device__ __forceinline__ float ftanh(float x) {
    float e = exp2f(x * 2.88539008f);
    return 1.0f - 2.0f * __builtin_amdgcn_rcpf(1.0f + e);
}

// W_hh fp32 [1024][256] -> bf16 fragment order:
// Wbf[((Tn*8+kc)*64+lane)*8 + j] = bf16(W_hh[16*Tn+(lane&15)][32*kc+(lane>>4)*8+j])
__global__ void wconv_kernel(const float* __restrict__ Whh,
                             unsigned short* __restrict__ Wbf) {
    int tid = blockIdx.x * blockDim.x + threadIdx.x;   // 0..32767
    int lane = tid & 63;
    int frag = tid >> 6;
    int Tn = frag >> 3;
    int kc = frag & 7;
    int n  = Tn * 16 + (lane & 15);
    int kb = kc * 32 + (lane >> 4) * 8;
    const float* src = Whh + (size_t)n * HID + kb;
    unsigned short* dst = Wbf + (size_t)tid * 8;
#pragma unroll
    for (int j = 0; j < 8; ++j) dst[j] = f2bf(src[j]);
}

#define MFMA8(ACC, BARR, BOFF)                                               \
    _Pragma("unroll")                                                        \
    for (int kc = 0; kc < 8; ++kc)                                           \
        ACC = __builtin_amdgcn_mfma_f32_16x16x32_bf16(afrag[kc],             \
                  BARR[(BOFF) + kc], ACC, 0, 0, 0);

// LDS-resident tile for this wave, slot = w*2 + S
#define LDSTILE(ACC, SLOT)                                                   \
    { v8bf bl_[8];                                                           \
      _Pragma("unroll")                                                      \
      for (int kc = 0; kc < 8; ++kc)                                         \
          bl_[kc] = __builtin_bit_cast(v8bf, *(const v4u*)(Wlds +            \
                      ((size_t)(((SLOT) * 8 + kc) * 64 + lane)) * 8));       \
      MFMA8(ACC, bl_, 0) }

// stream a tile by absolute tile index TN into SB
#define SLOADT(SB, TN)                                                       \
    _Pragma("unroll")                                                        \
    for (int kc = 0; kc < 8; ++kc)                                           \
        SB[kc] = __builtin_bit_cast(v8bf, *(const v4u*)(Wbf +                \
                   ((size_t)((TN) * 8 + kc) * 64 + lane) * 8));

#define INITG(S, AI, AF, AG, AO)                                             \
    { int nb = 16 * (w + 8 * (S)) + l4;                                      \
      float w0 = gw[nb],       b0 = gb[nb];                                  \
      float w1 = gw[256 + nb], b1 = gb[256 + nb];                            \
      float w2 = gw[512 + nb], b2 = gb[512 + nb];                            \
      float w3 = gw[768 + nb], b3 = gb[768 + nb];                            \
      _Pragma("unroll")                                                      \
      for (int r = 0; r < 4; ++r) {                                          \
          AI[r] = xv[r] * w0 + b0; AF[r] = xv[r] * w1 + b1;                  \
          AG[r] = xv[r] * w2 + b2; AO[r] = xv[r] * w3 + b3; } }

#define GATES(S, AI, AF, AG, AO)                                             \
    _Pragma("unroll")                                                        \
    for (int r = 0; r < 4; ++r) {                                            \
        float gi = fsigmoid(AI[r]);                                          \
        float gf = fsigmoid(AF[r]);                                          \
        float gg = ftanh(AG[r]);                                             \
        float go = fsigmoid(AO[r]);                                          \
        float cn = gf * c_st[(S) * 4 + r] + gi * gg;                         \
        c_st[(S) * 4 + r] = cn;                                              \
        hn_[(quad * 4 + r) * HPAD + 16 * (w + 8 * (S)) + l4] =               \
            f2bf(go * ftanh(cn));                                            \
    }

__global__ __launch_bounds__(THREADS, 2)
void lstm_kernel(const float* __restrict__ x,
                 const float* __restrict__ W_ih,
                 const float* __restrict__ b_ih,
                 const float* __restrict__ b_hh,
                 const float* __restrict__ W_lin,
                 const float* __restrict__ b_lin,
                 const unsigned short* __restrict__ Wbf,
                 float* __restrict__ out) {
    __shared__ __align__(16) unsigned short Wlds[16 * 8 * 64 * 8];   // 128 KB
    __shared__ __align__(16) unsigned short hbuf[2][BROWS * HPAD];   // 16.9 KB
    __shared__ float gw[1024];                                       // 4 KB
    __shared__ float gb[1024];                                       // 4 KB
    __shared__ float part[THREADS];                                  // 2 KB

    const int tid  = threadIdx.x;
    const int lane = tid & 63;
    const int w    = tid >> 6;      // wave 0..7
    const int l4   = lane & 15;
    const int quad = lane >> 4;
    const int r0   = blockIdx.x * BROWS;

    // gate consts -> LDS
    for (int i = tid; i < 1024; i += THREADS) {
        gw[i] = W_ih[i];
        gb[i] = b_ih[i] + b_hh[i];
    }
    // h(0) = 0
    for (int i = tid; i < BROWS * HPAD; i += THREADS) hbuf[0][i] = 0;

    // register-resident tiles: i,f gates both S: idx (S*2+G), Tn = 16*G + w + 8*S
    v8bf wres[32];
#pragma unroll
    for (int S = 0; S < 2; ++S)
#pragma unroll
        for (int G = 0; G < 2; ++G) {
            int Tn = 16 * G + w + 8 * S;
#pragma unroll
            for (int kc = 0; kc < 8; ++kc)
                wres[(S * 2 + G) * 8 + kc] = __builtin_bit_cast(v8bf,
                    *(const v4u*)(Wbf + ((size_t)(Tn * 8 + kc) * 64 + lane) * 8));
        }
    // LDS-resident g-gate tiles: slot w*2+S <- Tn = 32 + w + 8*S
#pragma unroll
    for (int S = 0; S < 2; ++S) {
        int Tn = 32 + w + 8 * S;
        int slot = w * 2 + S;
#pragma unroll
        for (int kc = 0; kc < 8; ++kc) {
            v4u d = *(const v4u*)(Wbf + ((size_t)(Tn * 8 + kc) * 64 + lane) * 8);
            *(v4u*)(Wlds + ((size_t)((slot * 8 + kc) * 64 + lane)) * 8) = d;
        }
    }
    __syncthreads();

    float c_st[8];
#pragma unroll
    for (int i = 0; i < 8; ++i) c_st[i] = 0.0f;

    // rotating stream buffer; prologue: o0 (Tn = 48 + w)
    v8bf sb[8];
    SLOADT(sb, 48 + w)

    int cur = 0;
    for (int t = 0; t < TT; ++t) {
        const unsigned short* hb = hbuf[cur];
        unsigned short* hn_ = hbuf[cur ^ 1];

        float xv[4];
#pragma unroll
        for (int r = 0; r < 4; ++r)
            xv[r] = x[(size_t)(r0 + quad * 4 + r) * TT + t];

        v8bf afrag[8];
        const unsigned short* hrow = hb + l4 * HPAD + quad * 8;
#pragma unroll
        for (int kc = 0; kc < 8; ++kc)
            afrag[kc] = __builtin_bit_cast(v8bf, *(const v4u*)(hrow + kc * 32));

        // ---- group S=0: i,f from regs; g from LDS; o = sb (prefetched) ----
        {
            v4f ai, af2, ag, ao;
            INITG(0, ai, af2, ag, ao)
            MFMA8(ai, wres, 0)              // i, S=0
            MFMA8(af2, wres, 8)             // f, S=0
            LDSTILE(ag, w * 2 + 0)          // g, S=0
            MFMA8(ao, sb, 0)                // o, S=0
            SLOADT(sb, 56 + w)              // load o,S=1 for this step
            GATES(0, ai, af2, ag, ao)
        }
        // ---- group S=1: i,f from regs; g from LDS; o = sb (just loaded) ----
        {
            v4f ai, af2, ag, ao;
            INITG(1, ai, af2, ag, ao)
            MFMA8(ai, wres, 16)             // i, S=1
            MFMA8(af2, wres, 24)            // f, S=1
            LDSTILE(ag, w * 2 + 1)          // g, S=1
            MFMA8(ao, sb, 0)                // o, S=1
            SLOADT(sb, 48 + w)              // cross-step prefetch o,S=0 for t+1
            GATES(1, ai, af2, ag, ao)
        }

        cur ^= 1;
        __syncthreads();
    }

    // Epilogue: out[b] = h_final . W_lin + b_lin
    {
        int rrow = tid >> 5, s5 = tid & 31;
        float p = 0.0f;
#pragma unroll
        for (int jj = 0; jj < 8; ++jj) {
            int j = s5 * 8 + jj;
            p += bf2f(hbuf[cur][rrow * HPAD + j]) * W_lin[j];
        }
        part[tid] = p;
    }
    __syncthreads();
    if (tid < 16) {
        float sum = 0.0f;
#pragma unroll
        for (int s = 0; s < 32; ++s) sum += part[tid * 32 + s];
        out[r0 + tid] = sum + b_lin[0];
    }
}

extern "C" void kernel_launch(void* const* d_in, const int* in_sizes, int n_in,
                              void* d_out, int out_size, void* d_ws, size_t ws_size,
                              hipStream_t stream) {
    const float* x     = (const float*)d_in[0];
    const float* W_ih  = (const float*)d_in[1];
    const float* W_hh  = (const float*)d_in[2];
    const float* b_ih  = (const float*)d_in[3];
    const float* b_hh  = (const float*)d_in[4];
    const float* W_lin = (const float*)d_in[5];
    const float* b_lin = (const float*)d_in[6];
    unsigned short* Wbf = (unsigned short*)d_ws;   // 512 KB

    wconv_kernel<<<128, 256, 0, stream>>>(W_hh, Wbf);
    lstm_kernel<<<NBLK, THREADS, 0, stream>>>(x, W_ih, b_ih, b_hh, W_lin, b_lin,
                                              Wbf, (float*)d_out);
}